// Round 4
// baseline (162.339 us; speedup 1.0000x reference)
//
#include <hip/hip_runtime.h>

#define H 1024
#define W 1024
#define F 32
#define K 25
#define TW 512            // output px per block (2 px per thread)
#define HALO 2
#define LROW (TW + 8)     // 520 floats per LDS row (halo 2 each side + pad)

typedef float f32x2 __attribute__((ext_vector_type(2)));

// Prep: transpose weights skv[f][k] -> wt[k][f] (contiguous f for s_load_dwordx8)
// and fold (dx,dy) into a single LDS dword offset per k.
__global__ __launch_bounds__(832) void prep(const float* __restrict__ skv,
                                            const int* __restrict__ idx,
                                            float* __restrict__ wt,
                                            int* __restrict__ loff) {
    const int i = threadIdx.x;
    if (i < F * K) {
        const int f = i % F, k = i / F;
        wt[i] = skv[f * K + k];            // wt[k*F + f]
    }
    if (i < K) {
        loff[i] = (idx[2 * i + 1] + HALO) * LROW + (idx[2 * i] + HALO);
    }
}

__global__ __launch_bounds__(256) void sparse_conv(const float* __restrict__ in,
                                                   const float* __restrict__ wt,
                                                   const int* __restrict__ loff,
                                                   float* __restrict__ out) {
    __shared__ float tile[5 * LROW];
    const int t  = threadIdx.x;
    const int x0 = blockIdx.x * TW;
    const int h  = blockIdx.y;

    // Stage rows h-2..h+2 (zero OOB). Interior via float2, halo cols by t<4.
    for (int r = 0; r < 5; ++r) {
        const int gy = h + r - HALO;
        const bool rowok = (gy >= 0 && gy < H);
        f32x2 v = (f32x2)(0.f, 0.f);
        if (rowok) v = *(const f32x2*)(in + (size_t)gy * W + x0 + 2 * t);
        *(f32x2*)&tile[r * LROW + HALO + 2 * t] = v;
        if (t < 4) {
            const int c  = (t < 2) ? t : (TW + HALO + (t - 2));
            const int gx = x0 + c - HALO;
            float hv = 0.f;
            if (rowok && gx >= 0 && gx < W) hv = in[(size_t)gy * W + gx];
            tile[r * LROW + c] = hv;
        }
    }
    __syncthreads();

    const size_t obase = (size_t)h * W + x0 + 2 * t;

    for (int fc = 0; fc < F; fc += 8) {          // f-chunks: compute 8, store 8
        float a0[8], a1[8];
        #pragma unroll
        for (int f = 0; f < 8; ++f) { a0[f] = 0.f; a1[f] = 0.f; }

        #pragma unroll
        for (int k = 0; k < K; ++k) {
            const float* p = &tile[loff[k] + 2 * t];   // s_load offset + v_add
            const float v0 = p[0];                     // ds_read2_b32
            const float v1 = p[1];
            #pragma unroll
            for (int f = 0; f < 8; ++f) {
                const float wv = wt[k * F + fc + f];   // uniform -> SGPR
                a0[f] = fmaf(wv, v0, a0[f]);
                a1[f] = fmaf(wv, v1, a1[f]);
            }
        }

        #pragma unroll
        for (int f = 0; f < 8; ++f) {
            f32x2 o;
            o.x = a0[f]; o.y = a1[f];
            __builtin_nontemporal_store(o, (f32x2*)(out + (size_t)(fc + f) * (H * W) + obase));
        }
    }
}

extern "C" void kernel_launch(void* const* d_in, const int* in_sizes, int n_in,
                              void* d_out, int out_size, void* d_ws, size_t ws_size,
                              hipStream_t stream) {
    const float* in  = (const float*)d_in[0];
    const float* skv = (const float*)d_in[1];
    const int*   idx = (const int*)d_in[2];
    float* out = (float*)d_out;
    float* wt  = (float*)d_ws;                          // 800 floats
    int*   loff = (int*)((char*)d_ws + 4096);           // 25 ints

    prep<<<1, 832, 0, stream>>>(skv, idx, wt, loff);
    sparse_conv<<<dim3(W / TW, H), dim3(256), 0, stream>>>(in, wt, loff, out);
}